// Round 1
// baseline (341.399 us; speedup 1.0000x reference)
//
#include <hip/hip_runtime.h>
#include <hip/hip_bf16.h>

// ---------------------------------------------------------------------------
// Problem shapes
//   B=1024, T=31, L=30, H=64, OUT_STEPS=20
//   bbox   [1024][31][4]
//   head   [1024][31][32][32]
//   conv1  1->4 3x3 VALID, relu, 2x2 maxpool  : 32->30->15
//   conv2  4->10 3x3 VALID, relu, 2x2 maxpool : 15->13->6
//   fc     360->5
//   enc GRU in=9 hid=64, 30 steps; dec GRU in=4 hid=64, 20 steps + lin 64->4
//   out [1024][20][4] = cumsum(dec outs) + bbox[:, -1]
// ---------------------------------------------------------------------------

#define B_    1024
#define L_    30
#define H_    64

__device__ __forceinline__ float sigmoid_f(float v) {
    return 1.f / (1.f + __expf(-v));
}
__device__ __forceinline__ float tanh_f(float v) {
    v = fminf(fmaxf(v, -15.f), 15.f);
    float e = __expf(2.f * v);
    return (e - 1.f) / (e + 1.f);
}
__device__ __forceinline__ void load4_lds(float* r, const float* p) {
    // p is 8B-aligned (even float index) by construction
    float2 a = *(const float2*)p;
    float2 b = *(const float2*)(p + 2);
    r[0] = a.x; r[1] = a.y; r[2] = b.x; r[3] = b.y;
}

// ---------------------------------------------------------------------------
// Kernel A: per-image conv encoder + fc -> enc_in[b][l][4..8]; diffs -> [0..3]
// grid = 30720 blocks x 64 threads (one image per block; 60 active threads
// in the strip stages).
// ---------------------------------------------------------------------------
__global__ __launch_bounds__(64) void conv_embed_kernel(
    const float* __restrict__ bbox,
    const float* __restrict__ head,
    const float* __restrict__ c1w, const float* __restrict__ c1b,
    const float* __restrict__ c2w, const float* __restrict__ c2b,
    const float* __restrict__ fcw, const float* __restrict__ fcb,
    float* __restrict__ enc_in)
{
    const int img = blockIdx.x;          // 0..30719
    const int b = img / L_;
    const int l = img % L_;
    const int tid = threadIdx.x;

    __shared__ float s_img[32 * 32];     // input image
    __shared__ float s_p1[4 * 15 * 16];  // pooled conv1 [c][py][px], width padded to 16
    __shared__ float s_p2[360];          // pooled conv2 flat [c*36 + py*6 + px]
    __shared__ float s_red[60];          // fc partials

    // ---- load image: 1024 floats / 64 threads = 4 float4 each -------------
    {
        const float4* src = (const float4*)(head + ((size_t)b * 31 + (size_t)l) * 1024);
        float4* dst = (float4*)s_img;
        #pragma unroll
        for (int i = 0; i < 4; ++i) dst[tid + 64 * i] = src[tid + 64 * i];
    }
    __syncthreads();

    // ---- stage 1: conv1 + relu + 2x2 maxpool -> s_p1 -----------------------
    // thread = (c in 0..3, px in 0..14); strip over py with rolling 4-row window
    if (tid < 60) {
        const int c = tid / 15, px = tid % 15;
        const int x0 = 2 * px;
        float w[9];
        #pragma unroll
        for (int k = 0; k < 9; ++k) w[k] = c1w[c * 9 + k];
        const float bias = c1b[c];

        float r0[4], r1[4], r2[4], r3[4];
        load4_lds(r0, s_img + 0 * 32 + x0);
        load4_lds(r1, s_img + 1 * 32 + x0);
        #pragma unroll
        for (int py = 0; py < 15; ++py) {
            load4_lds(r2, s_img + (2 * py + 2) * 32 + x0);
            load4_lds(r3, s_img + (2 * py + 3) * 32 + x0);
            float a00 = bias, a01 = bias, a10 = bias, a11 = bias;
            #pragma unroll
            for (int kx = 0; kx < 3; ++kx) {
                const float w0 = w[kx], w1 = w[3 + kx], w2 = w[6 + kx];
                a00 = fmaf(w0, r0[kx],     fmaf(w1, r1[kx],     fmaf(w2, r2[kx],     a00)));
                a01 = fmaf(w0, r0[kx + 1], fmaf(w1, r1[kx + 1], fmaf(w2, r2[kx + 1], a01)));
                a10 = fmaf(w0, r1[kx],     fmaf(w1, r2[kx],     fmaf(w2, r3[kx],     a10)));
                a11 = fmaf(w0, r1[kx + 1], fmaf(w1, r2[kx + 1], fmaf(w2, r3[kx + 1], a11)));
            }
            a00 = fmaxf(a00, 0.f); a01 = fmaxf(a01, 0.f);
            a10 = fmaxf(a10, 0.f); a11 = fmaxf(a11, 0.f);
            s_p1[c * 240 + py * 16 + px] = fmaxf(fmaxf(a00, a01), fmaxf(a10, a11));
            #pragma unroll
            for (int q = 0; q < 4; ++q) { r0[q] = r2[q]; r1[q] = r3[q]; }
        }
    }
    __syncthreads();

    // ---- stage 2: conv2 + relu + 2x2 maxpool -> s_p2 -----------------------
    // thread = (c in 0..9, px in 0..5); strip over py with rolling window
    if (tid < 60) {
        const int c = tid / 6, px = tid % 6;
        const int x0 = 2 * px;
        float w[4][9];
        #pragma unroll
        for (int ic = 0; ic < 4; ++ic)
            #pragma unroll
            for (int k = 0; k < 9; ++k) w[ic][k] = c2w[(c * 4 + ic) * 9 + k];
        const float bias = c2b[c];

        float win[4][4][4]; // [local row][ic][col]
        #pragma unroll
        for (int ic = 0; ic < 4; ++ic) {
            load4_lds(win[0][ic], s_p1 + ic * 240 + 0 * 16 + x0);
            load4_lds(win[1][ic], s_p1 + ic * 240 + 1 * 16 + x0);
        }
        #pragma unroll
        for (int py = 0; py < 6; ++py) {
            #pragma unroll
            for (int ic = 0; ic < 4; ++ic) {
                load4_lds(win[2][ic], s_p1 + ic * 240 + (2 * py + 2) * 16 + x0);
                load4_lds(win[3][ic], s_p1 + ic * 240 + (2 * py + 3) * 16 + x0);
            }
            float a00 = bias, a01 = bias, a10 = bias, a11 = bias;
            #pragma unroll
            for (int ic = 0; ic < 4; ++ic) {
                #pragma unroll
                for (int kx = 0; kx < 3; ++kx) {
                    const float w0 = w[ic][kx], w1 = w[ic][3 + kx], w2 = w[ic][6 + kx];
                    a00 = fmaf(w0, win[0][ic][kx],     fmaf(w1, win[1][ic][kx],     fmaf(w2, win[2][ic][kx],     a00)));
                    a01 = fmaf(w0, win[0][ic][kx + 1], fmaf(w1, win[1][ic][kx + 1], fmaf(w2, win[2][ic][kx + 1], a01)));
                    a10 = fmaf(w0, win[1][ic][kx],     fmaf(w1, win[2][ic][kx],     fmaf(w2, win[3][ic][kx],     a10)));
                    a11 = fmaf(w0, win[1][ic][kx + 1], fmaf(w1, win[2][ic][kx + 1], fmaf(w2, win[3][ic][kx + 1], a11)));
                }
            }
            a00 = fmaxf(a00, 0.f); a01 = fmaxf(a01, 0.f);
            a10 = fmaxf(a10, 0.f); a11 = fmaxf(a11, 0.f);
            s_p2[c * 36 + py * 6 + px] = fmaxf(fmaxf(a00, a01), fmaxf(a10, a11));
            #pragma unroll
            for (int ic = 0; ic < 4; ++ic)
                #pragma unroll
                for (int q = 0; q < 4; ++q) { win[0][ic][q] = win[2][ic][q]; win[1][ic][q] = win[3][ic][q]; }
        }
    }
    __syncthreads();

    // ---- stage 3: fc 360->5 partials ---------------------------------------
    if (tid < 60) {
        const int o = tid / 12, i0 = tid % 12;
        const float* wrow = fcw + o * 360;
        float acc = 0.f;
        #pragma unroll
        for (int k = 0; k < 30; ++k) {
            const int i = i0 + 12 * k;
            acc = fmaf(wrow[i], s_p2[i], acc);
        }
        s_red[tid] = acc;
    }
    __syncthreads();

    float* dst = enc_in + ((size_t)b * L_ + l) * 9;
    if (tid < 5) {
        float acc = fcb[tid];
        #pragma unroll
        for (int k = 0; k < 12; ++k) acc += s_red[tid * 12 + k];
        dst[4 + tid] = acc;
    } else if (tid >= 8 && tid < 12) {
        const int d = tid - 8;
        const float* bb = bbox + (size_t)b * 124 + (size_t)l * 4;
        dst[d] = bb[4 + d] - bb[d];  // diffs
    }
}

// ---------------------------------------------------------------------------
// Kernel B: GRU encoder. One block (4 waves x 64) per batch element.
// whh lives in registers: thread (w,j) holds whh[g*64+j][w*16 .. w*16+15] for
// g = 0,1,2. Cross-wave partial reduction through double-buffered LDS, one
// barrier per step; all waves redundantly replay the combine so h stays
// register-replicated.
// ---------------------------------------------------------------------------
__global__ __launch_bounds__(256) void gru_enc_kernel(
    const float* __restrict__ enc_in,   // [1024][30][9]
    const float* __restrict__ wih,      // [192][9]
    const float* __restrict__ whh,      // [192][64]
    const float* __restrict__ bih,      // [192]
    const float* __restrict__ bhh,      // [192]
    float* __restrict__ hn)             // [1024][64]
{
    const int b = blockIdx.x;
    const int tid = threadIdx.x;
    const int w = tid >> 6, j = tid & 63;

    float Wh[3][16];
    #pragma unroll
    for (int g = 0; g < 3; ++g) {
        const float* row = whh + (g * 64 + j) * 64 + w * 16;
        #pragma unroll
        for (int k = 0; k < 16; ++k) Wh[g][k] = row[k];
    }
    float Wi[3][9];
    #pragma unroll
    for (int g = 0; g < 3; ++g) {
        const float* row = wih + (g * 64 + j) * 9;
        #pragma unroll
        for (int k = 0; k < 9; ++k) Wi[g][k] = row[k];
    }
    const float bi0 = bih[j], bi1 = bih[64 + j], bi2 = bih[128 + j];
    const float bh0 = bhh[j], bh1 = bhh[64 + j], bh2 = bhh[128 + j];

    __shared__ float sp[2][4][3][64];
    float h = 0.f;
    const float* xp = enc_in + (size_t)b * (L_ * 9);

    for (int t = 0; t < L_; ++t) {
        const int pb = t & 1;
        // hidden-side partials over this wave's k-slice
        float pr = 0.f, pz = 0.f, pn = 0.f;
        #pragma unroll
        for (int k = 0; k < 16; ++k) {
            const float hk = __shfl(h, w * 16 + k);
            pr = fmaf(Wh[0][k], hk, pr);
            pz = fmaf(Wh[1][k], hk, pz);
            pn = fmaf(Wh[2][k], hk, pn);
        }
        sp[pb][w][0][j] = pr;
        sp[pb][w][1][j] = pz;
        sp[pb][w][2][j] = pn;

        // input-side gates (every wave computes — keeps h replicated)
        float x[9];
        #pragma unroll
        for (int k = 0; k < 9; ++k) x[k] = xp[t * 9 + k];
        float gr = bi0 + bh0, gz = bi1 + bh1, gni = bi2, gnh = bh2;
        #pragma unroll
        for (int k = 0; k < 9; ++k) {
            gr  = fmaf(Wi[0][k], x[k], gr);
            gz  = fmaf(Wi[1][k], x[k], gz);
            gni = fmaf(Wi[2][k], x[k], gni);
        }
        __syncthreads();
        #pragma unroll
        for (int ww = 0; ww < 4; ++ww) {
            gr  += sp[pb][ww][0][j];
            gz  += sp[pb][ww][1][j];
            gnh += sp[pb][ww][2][j];
        }
        const float r = sigmoid_f(gr);
        const float z = sigmoid_f(gz);
        const float n = tanh_f(gni + r * gnh);
        h = (1.f - z) * n + z * h;
    }
    if (w == 0) hn[(size_t)b * H_ + j] = h;
}

// ---------------------------------------------------------------------------
// Kernel C: autoregressive GRU decoder + linear head + cumsum + offset.
// Same per-block structure as the encoder.
// ---------------------------------------------------------------------------
__global__ __launch_bounds__(256) void gru_dec_kernel(
    const float* __restrict__ bbox,     // [1024][31][4]
    const float* __restrict__ hn,       // [1024][64]
    const float* __restrict__ wih,      // [192][4]
    const float* __restrict__ whh,      // [192][64]
    const float* __restrict__ bih,
    const float* __restrict__ bhh,
    const float* __restrict__ linw,     // [4][64]
    const float* __restrict__ linb,     // [4]
    float* __restrict__ out)            // [1024][20][4]
{
    const int b = blockIdx.x;
    const int tid = threadIdx.x;
    const int w = tid >> 6, j = tid & 63;

    float Wh[3][16];
    #pragma unroll
    for (int g = 0; g < 3; ++g) {
        const float* row = whh + (g * 64 + j) * 64 + w * 16;
        #pragma unroll
        for (int k = 0; k < 16; ++k) Wh[g][k] = row[k];
    }
    float Wi[3][4];
    #pragma unroll
    for (int g = 0; g < 3; ++g) {
        const float* row = wih + (g * 64 + j) * 4;
        #pragma unroll
        for (int k = 0; k < 4; ++k) Wi[g][k] = row[k];
    }
    const float bi0 = bih[j], bi1 = bih[64 + j], bi2 = bih[128 + j];
    const float bh0 = bhh[j], bh1 = bhh[64 + j], bh2 = bhh[128 + j];
    const float lw0 = linw[j], lw1 = linw[64 + j], lw2 = linw[128 + j], lw3 = linw[192 + j];
    const float lb0 = linb[0], lb1 = linb[1], lb2 = linb[2], lb3 = linb[3];

    float h = hn[(size_t)b * H_ + j];
    const float* bb = bbox + (size_t)b * 124;
    float px0 = bb[120] - bb[116];
    float px1 = bb[121] - bb[117];
    float px2 = bb[122] - bb[118];
    float px3 = bb[123] - bb[119];
    const float of0 = bb[120], of1 = bb[121], of2 = bb[122], of3 = bb[123];
    float cs0 = 0.f, cs1 = 0.f, cs2 = 0.f, cs3 = 0.f;

    __shared__ float sp[2][4][3][64];
    float* outp = out + (size_t)b * 80;

    for (int t = 0; t < 20; ++t) {
        const int pb = t & 1;
        float pr = 0.f, pz = 0.f, pn = 0.f;
        #pragma unroll
        for (int k = 0; k < 16; ++k) {
            const float hk = __shfl(h, w * 16 + k);
            pr = fmaf(Wh[0][k], hk, pr);
            pz = fmaf(Wh[1][k], hk, pz);
            pn = fmaf(Wh[2][k], hk, pn);
        }
        sp[pb][w][0][j] = pr;
        sp[pb][w][1][j] = pz;
        sp[pb][w][2][j] = pn;

        float gr = bi0 + bh0, gz = bi1 + bh1, gni = bi2, gnh = bh2;
        gr  = fmaf(Wi[0][0], px0, fmaf(Wi[0][1], px1, fmaf(Wi[0][2], px2, fmaf(Wi[0][3], px3, gr))));
        gz  = fmaf(Wi[1][0], px0, fmaf(Wi[1][1], px1, fmaf(Wi[1][2], px2, fmaf(Wi[1][3], px3, gz))));
        gni = fmaf(Wi[2][0], px0, fmaf(Wi[2][1], px1, fmaf(Wi[2][2], px2, fmaf(Wi[2][3], px3, gni))));

        __syncthreads();
        #pragma unroll
        for (int ww = 0; ww < 4; ++ww) {
            gr  += sp[pb][ww][0][j];
            gz  += sp[pb][ww][1][j];
            gnh += sp[pb][ww][2][j];
        }
        const float r = sigmoid_f(gr);
        const float z = sigmoid_f(gz);
        const float n = tanh_f(gni + r * gnh);
        h = (1.f - z) * n + z * h;

        // x_new = lin(h) + prev_x ; butterfly reduce over the 64-lane wave
        float v0 = lw0 * h, v1 = lw1 * h, v2 = lw2 * h, v3 = lw3 * h;
        #pragma unroll
        for (int s = 32; s > 0; s >>= 1) {
            v0 += __shfl_xor(v0, s);
            v1 += __shfl_xor(v1, s);
            v2 += __shfl_xor(v2, s);
            v3 += __shfl_xor(v3, s);
        }
        px0 = v0 + lb0 + px0;
        px1 = v1 + lb1 + px1;
        px2 = v2 + lb2 + px2;
        px3 = v3 + lb3 + px3;
        cs0 += px0; cs1 += px1; cs2 += px2; cs3 += px3;
        if (tid == 0) {
            outp[t * 4 + 0] = cs0 + of0;
            outp[t * 4 + 1] = cs1 + of1;
            outp[t * 4 + 2] = cs2 + of2;
            outp[t * 4 + 3] = cs3 + of3;
        }
    }
}

// ---------------------------------------------------------------------------
extern "C" void kernel_launch(void* const* d_in, const int* in_sizes, int n_in,
                              void* d_out, int out_size, void* d_ws, size_t ws_size,
                              hipStream_t stream) {
    (void)in_sizes; (void)n_in; (void)out_size; (void)ws_size;
    const float* bbox = (const float*)d_in[0];
    const float* head = (const float*)d_in[1];
    const float* c1w  = (const float*)d_in[2];
    const float* c1b  = (const float*)d_in[3];
    const float* c2w  = (const float*)d_in[4];
    const float* c2b  = (const float*)d_in[5];
    const float* fcw  = (const float*)d_in[6];
    const float* fcb  = (const float*)d_in[7];
    const float* ewih = (const float*)d_in[8];
    const float* ewhh = (const float*)d_in[9];
    const float* ebih = (const float*)d_in[10];
    const float* ebhh = (const float*)d_in[11];
    const float* dwih = (const float*)d_in[12];
    const float* dwhh = (const float*)d_in[13];
    const float* dbih = (const float*)d_in[14];
    const float* dbhh = (const float*)d_in[15];
    const float* linw = (const float*)d_in[16];
    const float* linb = (const float*)d_in[17];
    float* out = (float*)d_out;

    float* enc_in = (float*)d_ws;                       // 1024*30*9 floats
    float* hn     = enc_in + (size_t)B_ * L_ * 9;       // 1024*64 floats

    conv_embed_kernel<<<B_ * L_, 64, 0, stream>>>(bbox, head, c1w, c1b, c2w, c2b,
                                                  fcw, fcb, enc_in);
    gru_enc_kernel<<<B_, 256, 0, stream>>>(enc_in, ewih, ewhh, ebih, ebhh, hn);
    gru_dec_kernel<<<B_, 256, 0, stream>>>(bbox, hn, dwih, dwhh, dbih, dbhh,
                                           linw, linb, out);
}